// Round 10
// baseline (152.819 us; speedup 1.0000x reference)
//
#include <hip/hip_runtime.h>
#include <stdint.h>

// Qatten_Weight — Round 10: R4 scaffold + P1 B staged through LDS kf-slabs
// (double-buffered 16KB, depth-1 pipelined: loads for slab k+1 issue before
// compute of slab k; one barrier per slab). B read once per BLOCK (was twice
// per wave-pair) and MFMA feeds from LDS (~deterministic) instead of per-wave
// L2 loads (~500cyc). P2/P3/P1v direct loads (R4 verbatim); P4h register
// version (R7-proven); P5 epilogue R7 verbatim. LDS 63104B, 2 blocks/CU.
// B=16384 A=8 S=512 U=64 H=4 E=64 HE=256; BT=32, grid 512 x 256 threads.

typedef __attribute__((ext_vector_type(8))) short short8v;  // 8 bf16
typedef __attribute__((ext_vector_type(4))) float f32x4;

constexpr int BB = 16384, AA = 8, SS = 512, UU = 64, HH = 4, EE = 64, HE = 256;
constexpr int BT = 32;
constexpr int OUTV = BB * AA, OUTR = OUTV + BB, OUTE = OUTR + 1;

// packed fragment regions in ws (bf16 element offsets); frag = 512 elems = 1KB
constexpr int OFF_W1F  = 0;        // sel_w1: frag = h*256 + ftile*16 + kf   (1024)
constexpr int OFF_W2F  = 524288;   // sel_w2: frag = h*32  + etile*8  + kf   (128)
constexpr int OFF_VW1F = 589824;   // v_w1:   frag = etile*16 + kf           (64)
constexpr int OFF_KWF  = 622592;   // key_w:  frag = h*8 + utile*2 + kf      (32)
constexpr int PREP_N   = 638976;

__device__ __forceinline__ unsigned short f2bf(float x) {
  union { float f; uint32_t u; } v; v.f = x;
  uint32_t r = v.u + 0x7fffu + ((v.u >> 16) & 1u);   // RNE
  return (unsigned short)(r >> 16);
}
__device__ __forceinline__ float bf2f(short h) {
  union { uint32_t u; float f; } v; v.u = ((uint32_t)(unsigned short)h) << 16;
  return v.f;
}

// Pack: within a frag, element r = l*8 + j holds B[k = kf*32 + (l>>4)*8 + j]
// [col = tile*16 + (l&15)] — exactly the 16x16x32 B-fragment lane layout.
__global__ __launch_bounds__(256) void prep_kernel(
    const float* __restrict__ w1, const float* __restrict__ w2,
    const float* __restrict__ vw1, const float* __restrict__ kw,
    unsigned short* __restrict__ ws) {
  int idx = blockIdx.x * 256 + threadIdx.x;
  if (idx >= PREP_N) return;
  int r = idx & 511, l = r >> 3, j = r & 7, lr = l & 15, g = l >> 4;
  int fi = idx >> 9;
  float val;
  if (idx < OFF_W2F) {                    // B[k=s][col=f] for P1
    int h = fi >> 8, tl = (fi >> 4) & 15, kf = fi & 15;
    int s = kf * 32 + g * 8 + j, f = tl * 16 + lr;
    val = w1[((size_t)(h * SS) + s) * HE + f];
  } else if (idx < OFF_VW1F) {            // B[k=f][col=e] for P2
    fi -= OFF_W2F >> 9;
    int h = fi >> 5, tl = (fi >> 3) & 3, kf = fi & 7;
    int k = kf * 32 + g * 8 + j, e = tl * 16 + lr;
    val = w2[((size_t)(h * HE) + k) * EE + e];
  } else if (idx < OFF_KWF) {             // B[k=s][col=e] for P1v
    fi -= OFF_VW1F >> 9;
    int tl = fi >> 4, kf = fi & 15;
    int s = kf * 32 + g * 8 + j, e = tl * 16 + lr;
    val = vw1[(size_t)s * EE + e];
  } else {                                // B[k=e][col=u] for P3
    fi -= OFF_KWF >> 9;
    int h = fi >> 3, tl = (fi >> 1) & 3, kf = fi & 1;
    int k = kf * 32 + g * 8 + j, u = tl * 16 + lr;
    val = kw[((size_t)(h * UU) + u) * EE + k];
  }
  ws[idx] = f2bf(val);
}

__global__ __launch_bounds__(256) void qatten_mfma(
    const float* __restrict__ states, const float* __restrict__ sel_b1,
    const float* __restrict__ v_b1,  const float* __restrict__ v_w2,
    const float* __restrict__ v_b2,  const unsigned short* __restrict__ ws,
    float* __restrict__ out) {
  __shared__ __align__(16) unsigned char lds[63104];
  short* Bst  = (short*)lds;                 // 2 x 16KB slab buffers (32768 B)
  short* hmid = (short*)(lds + 32768);       // [32][264] bf16 (16896 B)
  short* sel  = (short*)(lds + 49664);       // [32][72]  bf16 ( 4608 B)
  short* mh   = (short*)(lds + 54272);       // [32][72]  bf16 ( 4608 B)
  float* logitsL = (float*)(lds + 58880);    // [32][33] f32   ( 4224 B)
  short* vhid = sel;                         // alias: sel dead after last P3
  float* wtsL = (float*)mh;                  // alias: mh dead after last P4h

  const int t  = threadIdx.x;
  const int w  = t >> 6, l = t & 63;
  const int mt = w & 1, nh = w >> 1;         // M-tile, N-half (R4 mapping)
  const int lr = l & 15, g = l >> 4;
  const int b0 = blockIdx.x * BT;
  const short* w1f  = (const short*)ws + OFF_W1F;
  const short* w2f  = (const short*)ws + OFF_W2F;
  const short* vw1f = (const short*)ws + OFF_VW1F;
  const short* kwf  = (const short*)ws + OFF_KWF;

  // ---- A-fragments: 16 rows of st, bf16, in registers (R4 verbatim) ----
  short8v aF[16];
  {
    const float* srow = states + (size_t)(b0 + mt * 16 + lr) * (AA * SS);
    #pragma unroll
    for (int f = 0; f < 16; ++f) {
      float4 p0 = *(const float4*)(srow + f * 32 + g * 8);
      float4 p1 = *(const float4*)(srow + f * 32 + g * 8 + 4);
      short8v a;
      a[0] = (short)f2bf(p0.x); a[1] = (short)f2bf(p0.y);
      a[2] = (short)f2bf(p0.z); a[3] = (short)f2bf(p0.w);
      a[4] = (short)f2bf(p1.x); a[5] = (short)f2bf(p1.y);
      a[6] = (short)f2bf(p1.z); a[7] = (short)f2bf(p1.w);
      aF[f] = a;
    }
  }

  for (int h = 0; h < HH; ++h) {
    const short* w1h = w1f + (size_t)(h * 256) * 512;   // head base (frags)
    // ---- P1 prologue: stage slab 0 (kf=0: frags ft*16+0, ft=0..15) ----
    {
      short8v stg0, stg1, stg2, stg3;
      {
        int lin0 = t,       ft0 = lin0 >> 6, of0 = (lin0 & 63) * 8;
        int lin1 = 256 + t, ft1 = lin1 >> 6, of1 = (lin1 & 63) * 8;
        int lin2 = 512 + t, ft2 = lin2 >> 6, of2 = (lin2 & 63) * 8;
        int lin3 = 768 + t, ft3 = lin3 >> 6, of3 = (lin3 & 63) * 8;
        stg0 = *(const short8v*)(w1h + (size_t)(ft0 * 16) * 512 + of0);
        stg1 = *(const short8v*)(w1h + (size_t)(ft1 * 16) * 512 + of1);
        stg2 = *(const short8v*)(w1h + (size_t)(ft2 * 16) * 512 + of2);
        stg3 = *(const short8v*)(w1h + (size_t)(ft3 * 16) * 512 + of3);
      }
      *(short8v*)(Bst + (0 * 256 + t) * 8) = stg0;
      *(short8v*)(Bst + (1 * 256 + t) * 8) = stg1;
      *(short8v*)(Bst + (2 * 256 + t) * 8) = stg2;
      *(short8v*)(Bst + (3 * 256 + t) * 8) = stg3;
    }
    __syncthreads();                     // slab 0 visible

    // ---- P1 main: 16 slabs, double-buffered, 1 barrier/slab ----
    f32x4 acc[8] = {{0,0,0,0},{0,0,0,0},{0,0,0,0},{0,0,0,0},
                    {0,0,0,0},{0,0,0,0},{0,0,0,0},{0,0,0,0}};
    #pragma unroll
    for (int k = 0; k < 16; ++k) {       // fully unrolled: aF[k] static
      short* bufc = Bst + (k & 1) * 8192;
      short* bufn = Bst + ((k & 1) ^ 1) * 8192;
      short8v stg0, stg1, stg2, stg3;
      if (k < 15) {                       // issue loads for slab k+1
        int lin0 = t,       ft0 = lin0 >> 6, of0 = (lin0 & 63) * 8;
        int lin1 = 256 + t, ft1 = lin1 >> 6, of1 = (lin1 & 63) * 8;
        int lin2 = 512 + t, ft2 = lin2 >> 6, of2 = (lin2 & 63) * 8;
        int lin3 = 768 + t, ft3 = lin3 >> 6, of3 = (lin3 & 63) * 8;
        stg0 = *(const short8v*)(w1h + (size_t)(ft0 * 16 + k + 1) * 512 + of0);
        stg1 = *(const short8v*)(w1h + (size_t)(ft1 * 16 + k + 1) * 512 + of1);
        stg2 = *(const short8v*)(w1h + (size_t)(ft2 * 16 + k + 1) * 512 + of2);
        stg3 = *(const short8v*)(w1h + (size_t)(ft3 * 16 + k + 1) * 512 + of3);
      }
      #pragma unroll
      for (int tl = 0; tl < 8; ++tl)      // 8 indep chains from LDS
        acc[tl] = __builtin_amdgcn_mfma_f32_16x16x32_bf16(
            aF[k], *(const short8v*)(bufc + (nh * 8 + tl) * 512 + l * 8),
            acc[tl], 0, 0, 0);
      if (k < 15) {                       // write slab k+1 (waits loads via dep)
        *(short8v*)(bufn + (0 * 256 + t) * 8) = stg0;
        *(short8v*)(bufn + (1 * 256 + t) * 8) = stg1;
        *(short8v*)(bufn + (2 * 256 + t) * 8) = stg2;
        *(short8v*)(bufn + (3 * 256 + t) * 8) = stg3;
      }
      __syncthreads();                    // slab k+1 visible; readers of k done
    }
    #pragma unroll
    for (int tl = 0; tl < 8; ++tl) {
      int fb = (nh * 8 + tl) * 16;
      float bias = sel_b1[h * HE + fb + lr];
      #pragma unroll
      for (int r2 = 0; r2 < 4; ++r2)
        hmid[(mt * 16 + g * 4 + r2) * 264 + fb + lr] =
            (short)f2bf(fmaxf(acc[tl][r2] + bias, 0.f));
    }
    __syncthreads();

    // ---- P2: sel = hmid @ sel_w2[h]; K-outer, 2 indep accs, K=256 ----
    f32x4 a2[2] = {{0,0,0,0},{0,0,0,0}};
    {
      const short* ah = hmid + (mt * 16 + lr) * 264 + g * 8;
      const short* b2 = w2f + ((size_t)(h * 32 + nh * 16)) * 512 + l * 8;
      #pragma unroll
      for (int kf = 0; kf < 8; ++kf) {
        short8v af = *(const short8v*)(ah + kf * 32);
        #pragma unroll
        for (int tl = 0; tl < 2; ++tl)
          a2[tl] = __builtin_amdgcn_mfma_f32_16x16x32_bf16(
              af, *(const short8v*)(b2 + (size_t)(tl * 8 + kf) * 512),
              a2[tl], 0, 0, 0);
      }
    }
    #pragma unroll
    for (int tl = 0; tl < 2; ++tl)
      #pragma unroll
      for (int r2 = 0; r2 < 4; ++r2)
        sel[(mt * 16 + g * 4 + r2) * 72 + (nh * 2 + tl) * 16 + lr] =
            (short)f2bf(a2[tl][r2]);
    __syncthreads();

    // ---- P3: m = sel @ key_w[h]^T; K-outer, 2 indep accs, K=64 ----
    f32x4 a3[2] = {{0,0,0,0},{0,0,0,0}};
    {
      const short* as = sel + (mt * 16 + lr) * 72 + g * 8;
      const short* b3 = kwf + ((size_t)(h * 8 + nh * 4)) * 512 + l * 8;
      #pragma unroll
      for (int kf = 0; kf < 2; ++kf) {
        short8v af = *(const short8v*)(as + kf * 32);
        #pragma unroll
        for (int tl = 0; tl < 2; ++tl)
          a3[tl] = __builtin_amdgcn_mfma_f32_16x16x32_bf16(
              af, *(const short8v*)(b3 + (size_t)(tl * 2 + kf) * 512),
              a3[tl], 0, 0, 0);
      }
    }
    #pragma unroll
    for (int tl = 0; tl < 2; ++tl)
      #pragma unroll
      for (int r2 = 0; r2 < 4; ++r2)
        mh[(mt * 16 + g * 4 + r2) * 72 + (nh * 2 + tl) * 16 + lr] =
            (short)f2bf(a3[tl][r2]);
    __syncthreads();

    // ---- P4h: logits from registers (static aF indices; R7-proven) ----
    {
      const short* mrow = mh + (mt * 16 + lr) * 72;
      short8v mv0 = *(const short8v*)(mrow + g * 8);
      short8v mv1 = *(const short8v*)(mrow + 32 + g * 8);
      #pragma unroll
      for (int a = 0; a < 8; ++a) {       // compile-time constant
        short8v a0 = aF[a * 2], a1 = aF[a * 2 + 1];
        float p = 0.f;
        #pragma unroll
        for (int j = 0; j < 8; ++j)
          p += bf2f(a0[j]) * bf2f(mv0[j]) + bf2f(a1[j]) * bf2f(mv1[j]);
        p += __shfl_xor(p, 16);
        p += __shfl_xor(p, 32);
        if (g == 0 && (a >> 2) == nh)
          logitsL[(mt * 16 + lr) * 33 + h * 8 + a] = p;
      }
    }
    __syncthreads();   // P4h mh reads done; next head's P1 rewrites Bst only
  }

  // ---- P1v: vhid = relu(st @ v_w1 + b1); K-outer, 2 indep accs ----
  {
    f32x4 av[2] = {{0,0,0,0},{0,0,0,0}};
    const short* bv = vw1f + ((size_t)(nh * 32)) * 512 + l * 8;
    #pragma unroll
    for (int kf = 0; kf < 16; ++kf) {
      short8v af = aF[kf];
      #pragma unroll
      for (int tl = 0; tl < 2; ++tl)
        av[tl] = __builtin_amdgcn_mfma_f32_16x16x32_bf16(
            af, *(const short8v*)(bv + (size_t)(tl * 16 + kf) * 512),
            av[tl], 0, 0, 0);
    }
    #pragma unroll
    for (int tl = 0; tl < 2; ++tl) {
      int eb = (nh * 2 + tl) * 16;
      float bias = v_b1[eb + lr];
      #pragma unroll
      for (int r2 = 0; r2 < 4; ++r2)
        vhid[(mt * 16 + g * 4 + r2) * 72 + eb + lr] =
            (short)f2bf(fmaxf(av[tl][r2] + bias, 0.f));
    }
  }
  __syncthreads();

  // ---- v finalize (reads vhid) ----
  {
    int b = t >> 3, r = t & 7;
    short8v hv = *(const short8v*)(vhid + b * 72 + r * 8);
    float p = 0.f;
    #pragma unroll
    for (int j = 0; j < 8; ++j) p += bf2f(hv[j]) * v_w2[r * 8 + j];
    p += __shfl_xor(p, 1); p += __shfl_xor(p, 2); p += __shfl_xor(p, 4);
    if (r == 0) out[OUTV + b0 + b] = p + v_b2[0];
  }
  __syncthreads();

  // ---- P5: softmax, entropy, reg (R7 verbatim) ----
  if (t < 128) {
    int b = t >> 2, hh = t & 3;
    float sc[8];
    float rp = 0.f, mx = -1e30f;
    #pragma unroll
    for (int a = 0; a < 8; ++a) {
      float lg = logitsL[b * 33 + hh * 8 + a];
      rp += lg * lg;
      sc[a] = lg * 0.125f;
      mx = fmaxf(mx, sc[a]);
    }
    float sum = 0.f;
    #pragma unroll
    for (int a = 0; a < 8; ++a) { sc[a] = __expf(sc[a] - mx); sum += sc[a]; }
    float inv = 1.f / sum, ent = 0.f;
    #pragma unroll
    for (int a = 0; a < 8; ++a) {
      float wv = sc[a] * inv;
      wtsL[b * 33 + hh * 8 + a] = wv;
      ent += wv * __logf(wv + 1e-8f);
    }
    #pragma unroll
    for (int off = 1; off <= 32; off <<= 1) rp += __shfl_xor(rp, off);
    if ((t & 63) == 0)
      atomicAdd(out + OUTR, rp * (0.001f / ((float)BB * (float)AA)));
    float ep = ent;
    #pragma unroll
    for (int off = 4; off <= 32; off <<= 1) ep += __shfl_xor(ep, off);
    if ((t & 63) < 4) atomicAdd(out + OUTE + hh, -ep / (float)BB);
  }
  __syncthreads();
  {
    int b = t >> 3, a = t & 7;
    out[(size_t)(b0 + b) * AA + a] = wtsL[b * 33 + a] + wtsL[b * 33 + 8 + a] +
                                     wtsL[b * 33 + 16 + a] + wtsL[b * 33 + 24 + a];
  }
}

extern "C" void kernel_launch(void* const* d_in, const int* in_sizes, int n_in,
                              void* d_out, int out_size, void* d_ws, size_t ws_size,
                              hipStream_t stream) {
  (void)in_sizes; (void)n_in; (void)ws_size; (void)out_size;
  const float* states = (const float*)d_in[1];
  const float* sel_w1 = (const float*)d_in[3];
  const float* sel_b1 = (const float*)d_in[4];
  const float* sel_w2 = (const float*)d_in[5];
  const float* key_w  = (const float*)d_in[6];
  const float* v_w1   = (const float*)d_in[7];
  const float* v_b1   = (const float*)d_in[8];
  const float* v_w2   = (const float*)d_in[9];
  const float* v_b2   = (const float*)d_in[10];
  float* out = (float*)d_out;
  unsigned short* ws = (unsigned short*)d_ws;

  hipMemsetAsync(out + OUTR, 0, 5 * sizeof(float), stream);
  prep_kernel<<<(PREP_N + 255) / 256, 256, 0, stream>>>(sel_w1, sel_w2, v_w1,
                                                        key_w, ws);
  qatten_mfma<<<BB / BT, 256, 0, stream>>>(states, sel_b1, v_b1, v_w2, v_b2,
                                           ws, out);
}